// Round 12
// baseline (1979.749 us; speedup 1.0000x reference)
//
#include <hip/hip_runtime.h>
#include <hip/hip_bf16.h>
#include <hip/hip_fp16.h>

#define NB 32
#define NS 1024
#define NH 1024

typedef short s16x4 __attribute__((ext_vector_type(4)));
typedef short s16x8 __attribute__((ext_vector_type(8)));
typedef float f32x4 __attribute__((ext_vector_type(4)));

typedef __attribute__((address_space(3))) void lds_void;
typedef const __attribute__((address_space(1))) void gmem_void;

__device__ __forceinline__ short f2bf(float f) {
  __hip_bfloat16 h = __float2bfloat16(f);
  return *reinterpret_cast<short*>(&h);
}
__device__ __forceinline__ float bf2f(short s) {
  union { unsigned u; float f; } cv;
  cv.u = ((unsigned)(unsigned short)s) << 16;
  return cv.f;
}
__device__ __forceinline__ short f2h(float f) {
  __half h = __float2half_rn(f);
  return *reinterpret_cast<short*>(&h);
}
__device__ __forceinline__ float h2f(short s) {
  __half h = *reinterpret_cast<__half*>(&s);
  return __half2float(h);
}

__device__ __forceinline__ float wave_reduce_sum(float v) {
#pragma unroll
  for (int o = 32; o; o >>= 1) v += __shfl_xor(v, o);
  return v;
}
__device__ __forceinline__ float wave_reduce_max(float v) {
#pragma unroll
  for (int o = 32; o; o >>= 1) v = fmaxf(v, __shfl_xor(v, o));
  return v;
}
__device__ __forceinline__ float block_reduce_sum(float v, float* red) {
  v = wave_reduce_sum(v);
  __syncthreads();
  if ((threadIdx.x & 63) == 0) red[threadIdx.x >> 6] = v;
  __syncthreads();
  return red[0] + red[1] + red[2] + red[3];
}
__device__ __forceinline__ float block_reduce_max(float v, float* red) {
  v = wave_reduce_max(v);
  __syncthreads();
  if ((threadIdx.x & 63) == 0) red[threadIdx.x >> 6] = v;
  __syncthreads();
  return fmaxf(fmaxf(red[0], red[1]), fmaxf(red[2], red[3]));
}

#define BAR1 do { __builtin_amdgcn_s_barrier();                              \
                  asm volatile("s_waitcnt lgkmcnt(0)" ::: "memory");         \
                  __builtin_amdgcn_sched_barrier(0); } while (0)
#define BAR2 do { __builtin_amdgcn_s_barrier();                              \
                  asm volatile("" ::: "memory"); } while (0)
#define VW   asm volatile("s_waitcnt vmcnt(4)" ::: "memory")
#define VW2  asm volatile("s_waitcnt vmcnt(2)" ::: "memory")
#define VW1  asm volatile("s_waitcnt vmcnt(1)" ::: "memory")
#define VW0  asm volatile("s_waitcnt vmcnt(0)" ::: "memory")

// ==================== BK=64 core (r8+peel, proven) — used by qkv ============
#define GEMM_PRE()                                                           \
  const int tid  = threadIdx.x;                                              \
  const int lane = tid & 63;                                                 \
  const int w    = tid >> 6;                                                 \
  const int wm   = w >> 2, wn = w & 3;                                       \
  const int fr   = lane & 15, fq = lane >> 4;                                \
  const long tA  = (long)(tid >> 3) * 1024 +                                 \
                   (((tid & 7) ^ ((tid >> 3) & 7)) << 3);                    \
  const int kc0  = (fq * 8) ^ ((fr & 7) * 8);                                \
  const int kc1  = (fq * 8 + 32) ^ ((fr & 7) * 8);                           \
  const int rdA  = wm * 8192 + fr * 64;                                      \
  const int rdB  = 16384 + (wn >> 1) * 8192 + (wn & 1) * 4096 + fr * 64;     \
  const int wsl  = w * 512;                                                  \
  f32x4 acc[8][4];                                                           \
  s16x8 aF[2][4][2], bF[2][2][2];                                            \
  _Pragma("unroll") for (int i_ = 0; i_ < 8; ++i_)                           \
    _Pragma("unroll") for (int j_ = 0; j_ < 4; ++j_)                         \
      acc[i_][j_] = (f32x4){0.f, 0.f, 0.f, 0.f};

#define STAGE(d, isB, h, kt)                                                 \
  do {                                                                       \
    const short* _g = ((isB) ? gB + (n0 + (h) * 128) * 1024                  \
                             : gA + (m0 + (h) * 128) * 1024) +               \
                      (long)(kt) * 64 + tA;                                  \
    short* _l = lds + (d) * 32768 + (isB) * 16384 + (h) * 8192 + wsl;        \
    __builtin_amdgcn_global_load_lds((gmem_void*)_g, (lds_void*)_l,          \
                                     16, 0, 0);                              \
    __builtin_amdgcn_global_load_lds((gmem_void*)(_g + 65536),               \
                                     (lds_void*)(_l + 4096), 16, 0, 0);      \
  } while (0)

#define RD_A(d, mq)                                                          \
  _Pragma("unroll") for (int mi = 0; mi < 4; ++mi) {                         \
    aF[mq][mi][0] = *(const s16x8*)(lds + (d) * 32768 + rdA + (mq) * 4096 +  \
                                    mi * 1024 + kc0);                        \
    aF[mq][mi][1] = *(const s16x8*)(lds + (d) * 32768 + rdA + (mq) * 4096 +  \
                                    mi * 1024 + kc1);                        \
  }
#define RD_B(d, nq)                                                          \
  _Pragma("unroll") for (int ni = 0; ni < 2; ++ni) {                         \
    bF[nq][ni][0] = *(const s16x8*)(lds + (d) * 32768 + rdB + (nq) * 2048 +  \
                                    ni * 1024 + kc0);                        \
    bF[nq][ni][1] = *(const s16x8*)(lds + (d) * 32768 + rdB + (nq) * 2048 +  \
                                    ni * 1024 + kc1);                        \
  }
#define MMA(mq, nq)                                                          \
  do {                                                                       \
    __builtin_amdgcn_s_setprio(1);                                           \
    _Pragma("unroll") for (int kk = 0; kk < 2; ++kk)                         \
      _Pragma("unroll") for (int mi = 0; mi < 4; ++mi)                       \
        _Pragma("unroll") for (int ni = 0; ni < 2; ++ni)                     \
          acc[(mq) * 4 + mi][(nq) * 2 + ni] =                                \
              __builtin_amdgcn_mfma_f32_16x16x32_bf16(                       \
                  aF[mq][mi][kk], bF[nq][ni][kk],                            \
                  acc[(mq) * 4 + mi][(nq) * 2 + ni], 0, 0, 0);               \
    __builtin_amdgcn_s_setprio(0);                                           \
  } while (0)

#define GEMM_MAIN()                                                          \
  GEMM_PRE();                                                                \
  STAGE(0, 1, 0, 0); STAGE(0, 1, 1, 0); STAGE(0, 0, 0, 0); STAGE(0, 0, 1, 0);\
  STAGE(1, 1, 0, 1); STAGE(1, 1, 1, 1);                                      \
  VW; BAR2;                                                                  \
  RD_A(0, 0);                                                                \
  for (int it = 0; it < 7; ++it) {                                           \
    const int t1 = 2 * it + 1, t2 = 2 * it + 2, t3 = 2 * it + 3;             \
    RD_B(0, 0); STAGE(1, 0, 0, t1); BAR1; MMA(0, 0); BAR2;                   \
    RD_B(0, 1); STAGE(1, 0, 1, t1); BAR1; MMA(0, 1); BAR2;                   \
    RD_A(0, 1); STAGE(0, 1, 0, t2); BAR1; MMA(1, 1); BAR2;                   \
    VW2;        STAGE(0, 1, 1, t2); BAR1; RD_A(1, 0); MMA(1, 0); BAR2;       \
    RD_B(1, 0); STAGE(0, 0, 0, t2); BAR1; MMA(0, 0); BAR2;                   \
    RD_B(1, 1); STAGE(0, 0, 1, t2); BAR1; MMA(0, 1); BAR2;                   \
    RD_A(1, 1); STAGE(1, 1, 0, t3); BAR1; MMA(1, 1); BAR2;                   \
    VW2;        STAGE(1, 1, 1, t3); BAR1; RD_A(0, 0); MMA(1, 0); BAR2;       \
  }                                                                          \
  RD_B(0, 0); STAGE(1, 0, 0, 15); BAR1; MMA(0, 0); BAR2;                     \
  RD_B(0, 1); STAGE(1, 0, 1, 15); BAR1; MMA(0, 1); BAR2;                     \
  RD_A(0, 1);                     BAR1; MMA(1, 1); BAR2;                     \
  VW0;                            BAR1; RD_A(1, 0); MMA(1, 0); BAR2;         \
  RD_B(1, 0);                     BAR1; MMA(0, 0); BAR2;                     \
  RD_B(1, 1);                     BAR1; MMA(0, 1); BAR2;                     \
  RD_A(1, 1);                     BAR1; MMA(1, 1); BAR2;                     \
  VW0;                            BAR1; MMA(1, 0); BAR2;

// ==================== BK=32 core — 64 KiB LDS, 2 blocks/CU (escore/av) =====
// Same 8-phase schedule; STAGE = 1 gload_lds (half-tile 8 KB); waits
// recounted: prologue vmcnt(2), ph4/ph8 vmcnt(1), peel vmcnt(0).
// 64-B rows: swizzle slot = col8 ^ ((row>>1)&3) (involution both sides,
// 16 lanes -> 8 bank-positions = 2-way, free per m136).
#define GEMM32_PRE()                                                         \
  const int tid  = threadIdx.x;                                              \
  const int lane = tid & 63;                                                 \
  const int w    = tid >> 6;                                                 \
  const int wm   = w >> 2, wn = w & 3;                                       \
  const int fr   = lane & 15, fq = lane >> 4;                                \
  const long tA32 = (long)(tid >> 2) * 1024 +                                \
                    (((tid & 3) ^ ((tid >> 3) & 3)) << 3);                   \
  const int kc32 = (fq ^ ((fr >> 1) & 3)) << 3;                              \
  const int rdA32 = wm * 4096 + fr * 32 + kc32;                              \
  const int rdB32 = 8192 + (wn >> 1) * 4096 + (wn & 1) * 2048 +              \
                    fr * 32 + kc32;                                          \
  const int wsl32 = w * 512;                                                 \
  f32x4 acc[8][4];                                                           \
  s16x8 aF2[2][4], bF2[2][2];                                                \
  _Pragma("unroll") for (int i_ = 0; i_ < 8; ++i_)                           \
    _Pragma("unroll") for (int j_ = 0; j_ < 4; ++j_)                         \
      acc[i_][j_] = (f32x4){0.f, 0.f, 0.f, 0.f};

#define STAGE32(d, isB, h, kt)                                               \
  do {                                                                       \
    const short* _g = ((isB) ? gB + (n0 + (h) * 128) * 1024                  \
                             : gA + (m0 + (h) * 128) * 1024) +               \
                      (long)(kt) * 32 + tA32;                                \
    short* _l = lds + (d) * 16384 + (isB) * 8192 + (h) * 4096 + wsl32;       \
    __builtin_amdgcn_global_load_lds((gmem_void*)_g, (lds_void*)_l,          \
                                     16, 0, 0);                              \
  } while (0)

#define RD_A32(d, mq)                                                        \
  _Pragma("unroll") for (int mi = 0; mi < 4; ++mi)                           \
    aF2[mq][mi] = *(const s16x8*)(lds + (d) * 16384 + rdA32 +                \
                                  (mq) * 2048 + mi * 512);
#define RD_B32(d, nq)                                                        \
  _Pragma("unroll") for (int ni = 0; ni < 2; ++ni)                           \
    bF2[nq][ni] = *(const s16x8*)(lds + (d) * 16384 + rdB32 +                \
                                  (nq) * 1024 + ni * 512);
#define MMA32(mq, nq)                                                        \
  do {                                                                       \
    __builtin_amdgcn_s_setprio(1);                                           \
    _Pragma("unroll") for (int mi = 0; mi < 4; ++mi)                         \
      _Pragma("unroll") for (int ni = 0; ni < 2; ++ni)                       \
        acc[(mq) * 4 + mi][(nq) * 2 + ni] =                                  \
            __builtin_amdgcn_mfma_f32_16x16x32_bf16(                         \
                aF2[mq][mi], bF2[nq][ni],                                    \
                acc[(mq) * 4 + mi][(nq) * 2 + ni], 0, 0, 0);                 \
    __builtin_amdgcn_s_setprio(0);                                           \
  } while (0)

#define GEMM32_MAIN()                                                        \
  GEMM32_PRE();                                                              \
  STAGE32(0, 1, 0, 0); STAGE32(0, 1, 1, 0);                                  \
  STAGE32(0, 0, 0, 0); STAGE32(0, 0, 1, 0);                                  \
  STAGE32(1, 1, 0, 1); STAGE32(1, 1, 1, 1);                                  \
  VW2; BAR2;                                                                 \
  RD_A32(0, 0);                                                              \
  for (int it = 0; it < 15; ++it) {                                          \
    const int t1 = 2 * it + 1, t2 = 2 * it + 2, t3 = 2 * it + 3;             \
    RD_B32(0, 0); STAGE32(1, 0, 0, t1); BAR1; MMA32(0, 0); BAR2;             \
    RD_B32(0, 1); STAGE32(1, 0, 1, t1); BAR1; MMA32(0, 1); BAR2;             \
    RD_A32(0, 1); STAGE32(0, 1, 0, t2); BAR1; MMA32(1, 1); BAR2;             \
    VW1;          STAGE32(0, 1, 1, t2); BAR1; RD_A32(1, 0); MMA32(1, 0); BAR2;\
    RD_B32(1, 0); STAGE32(0, 0, 0, t2); BAR1; MMA32(0, 0); BAR2;             \
    RD_B32(1, 1); STAGE32(0, 0, 1, t2); BAR1; MMA32(0, 1); BAR2;             \
    RD_A32(1, 1); STAGE32(1, 1, 0, t3); BAR1; MMA32(1, 1); BAR2;             \
    VW1;          STAGE32(1, 1, 1, t3); BAR1; RD_A32(0, 0); MMA32(1, 0); BAR2;\
  }                                                                          \
  RD_B32(0, 0); STAGE32(1, 0, 0, 31); BAR1; MMA32(0, 0); BAR2;               \
  RD_B32(0, 1); STAGE32(1, 0, 1, 31); BAR1; MMA32(0, 1); BAR2;               \
  RD_A32(0, 1);                       BAR1; MMA32(1, 1); BAR2;               \
  VW0;                                BAR1; RD_A32(1, 0); MMA32(1, 0); BAR2; \
  RD_B32(1, 0);                       BAR1; MMA32(0, 0); BAR2;               \
  RD_B32(1, 1);                       BAR1; MMA32(0, 1); BAR2;               \
  RD_A32(1, 1);                       BAR1; MMA32(1, 1); BAR2;               \
  VW0;                                BAR1; MMA32(1, 0); BAR2;

// epilogue index map (both cores): row = m0 + wm*128 + mI*16 + fq*4 + r
//                                  col = n0 + wn*64  + nI*16 + fr

// ---- prep: [0,1024) rel-GEMV per g; [1024,1056) sub-gather; rest cvtw
__global__ __launch_bounds__(256) void prep_kernel(const int* __restrict__ relation,
    const float* __restrict__ x, const int* __restrict__ sub_head,
    const int* __restrict__ sub_tail, const float* __restrict__ rel_emb,
    const float* __restrict__ Wrf, const float* __restrict__ brf,
    float* __restrict__ cond,
    const float* __restrict__ Wq, const float* __restrict__ Wk,
    const float* __restrict__ Wv, short* __restrict__ wout) {
  const int blk = blockIdx.x;
  const int tid = threadIdx.x;
  if (blk >= 1056) {
    long i = ((long)(blk - 1056) * 256 + tid) * 4;
    int seg = (int)(i >> 20);
    long off = i & 1048575;
    const float* src = seg == 0 ? Wq : (seg == 1 ? Wk : Wv);
    f32x4 v = *(const f32x4*)(src + off);
    s16x4 o = { f2bf(v[0]), f2bf(v[1]), f2bf(v[2]), f2bf(v[3]) };
    *(s16x4*)(wout + i) = o;
    return;
  }
  if (blk >= 1024) {
    const int b = blk - 1024;
    const int sh = sub_head[b], st = sub_tail[b];
    for (int h = tid * 4; h < NH; h += 1024) {
      f32x4 a = *(const f32x4*)(x + ((long)b * NS + sh) * NH + h);
      f32x4 c = *(const f32x4*)(x + ((long)b * NS + st) * NH + h);
      f32x4 o = { 0.5f * (a[0] + c[0]), 0.5f * (a[1] + c[1]),
                  0.5f * (a[2] + c[2]), 0.5f * (a[3] + c[3]) };
      *(f32x4*)(cond + b * 2 * NH + NH + h) = o;
    }
    return;
  }
  const int g = blk;
  __shared__ float wr[NH];
  for (int h = tid * 4; h < NH; h += 1024)
    *(f32x4*)(wr + h) = *(const f32x4*)(Wrf + (long)g * NH + h);
  __syncthreads();
  const int lane = tid & 63, wid = tid >> 6;
  const float bg = brf[g];
  for (int b = wid; b < NB; b += 4) {
    const int rid = relation[b];
    const float* re = rel_emb + (long)rid * NH;
    float s = 0.f;
#pragma unroll
    for (int h = lane * 4; h < NH; h += 256) {
      f32x4 rv = *(const f32x4*)(re + h);
      f32x4 wv = *(const f32x4*)(wr + h);
      s += rv[0] * wv[0] + rv[1] * wv[1] + rv[2] * wv[2] + rv[3] * wv[3];
    }
    s = wave_reduce_sum(s);
    if (lane == 0) cond[b * 2 * NH + g] = fminf(fmaxf(s + bg, 0.f), 6.f);
  }
}

// ---- wln/bln[b,g] = cond[b,:] . W{wd,bd}[g,:] + cln_{w,b}[g]
__global__ __launch_bounds__(256) void wb_kernel(const float* __restrict__ cond,
    const float* __restrict__ Wwd, const float* __restrict__ Wbd,
    const float* __restrict__ cln_w, const float* __restrict__ cln_b,
    float* __restrict__ wln, float* __restrict__ bln) {
  const int g = blockIdx.x;
  const int tid = threadIdx.x;
  __shared__ float wrow[2 * NH];
  __shared__ float brow[2 * NH];
  for (int i = tid * 4; i < 2 * NH; i += 1024) {
    *(f32x4*)(wrow + i) = *(const f32x4*)(Wwd + (long)g * 2 * NH + i);
    *(f32x4*)(brow + i) = *(const f32x4*)(Wbd + (long)g * 2 * NH + i);
  }
  __syncthreads();
  const int lane = tid & 63, wid = tid >> 6;
  const float cw = cln_w[g], cb = cln_b[g];
  for (int b = wid; b < NB; b += 4) {
    float sw = 0.f, sb = 0.f;
#pragma unroll
    for (int c = lane * 4; c < 2 * NH; c += 256) {
      f32x4 cv = *(const f32x4*)(cond + b * 2 * NH + c);
      f32x4 wv = *(const f32x4*)(wrow + c);
      f32x4 bv = *(const f32x4*)(brow + c);
      sw += cv[0] * wv[0] + cv[1] * wv[1] + cv[2] * wv[2] + cv[3] * wv[3];
      sb += cv[0] * bv[0] + cv[1] * bv[1] + cv[2] * bv[2] + cv[3] * bv[3];
    }
    sw = wave_reduce_sum(sw);
    sb = wave_reduce_sum(sb);
    if (lane == 0) {
      wln[b * NH + g] = sw + cw;
      bln[b * NH + g] = sb + cb;
    }
  }
}

// ---- conditional LayerNorm -> normed (bf16)
__global__ __launch_bounds__(256) void ln_kernel(const float* __restrict__ x,
    const float* __restrict__ wln, const float* __restrict__ bln, short* __restrict__ normed) {
  const long row = blockIdx.x;
  const int tid = threadIdx.x;
  const long b = row >> 10;
  __shared__ float red[4];
  f32x4 v = *(const f32x4*)(x + row * NH + tid * 4);
  float mean = block_reduce_sum(v[0] + v[1] + v[2] + v[3], red) * (1.f / NH);
  float c0 = v[0] - mean, c1 = v[1] - mean, c2 = v[2] - mean, c3 = v[3] - mean;
  float var = block_reduce_sum(c0 * c0 + c1 * c1 + c2 * c2 + c3 * c3, red) * (1.f / NH);
  float rstd = rsqrtf(var + 1e-12f);
  f32x4 wv = *(const f32x4*)(wln + b * NH + tid * 4);
  f32x4 bv = *(const f32x4*)(bln + b * NH + tid * 4);
  s16x4 o = { f2bf(c0 * rstd * wv[0] + bv[0]), f2bf(c1 * rstd * wv[1] + bv[1]),
              f2bf(c2 * rstd * wv[2] + bv[2]), f2bf(c3 * rstd * wv[3] + bv[3]) };
  *(s16x4*)(normed + row * NH + tid * 4) = o;
}

// ---- fused qkv GEMM (BK=64 core): 1536 wgs, XCD-chunked swizzle.
// v is transposed via LDS ([256 h][264-pad t]) for coalesced vT stores.
__global__ __launch_bounds__(512, 2) void qkv_kernel(const short* __restrict__ A,
    const short* __restrict__ Wqkv,
    const float* __restrict__ bq, const float* __restrict__ bk, const float* __restrict__ bv,
    short* __restrict__ q, short* __restrict__ k, short* __restrict__ vT) {
  __shared__ short lds[67584];  // 135168 B: 128K staging, reused for vT transpose
  const int flat = blockIdx.y * 12 + blockIdx.x;
  const int gid  = (flat & 7) * 192 + (flat >> 3);
  const int mt = gid / 12, nt = gid % 12;
  const short* gA = A;
  const short* gB = Wqkv;
  const long n0 = (long)nt * 256;
  const long m0 = (long)mt * 256;
  GEMM_MAIN();
  const int z = nt >> 2;
  const long hc0 = (long)(nt & 3) * 256;
  const float* bias = z == 0 ? bq : (z == 1 ? bk : bv);
  if (z < 2) {
    short* dst = z == 0 ? q : k;
#pragma unroll
    for (int nI = 0; nI < 4; ++nI) {
      const long col = hc0 + wn * 64 + nI * 16 + fr;
      const float bcol = bias[col];
#pragma unroll
      for (int mI = 0; mI < 8; ++mI)
#pragma unroll
        for (int r = 0; r < 4; ++r) {
          const long row = m0 + wm * 128 + mI * 16 + fq * 4 + r;
          dst[row * NH + col] = f2bf(fmaxf(acc[mI][nI][r] + bcol, 0.f));
        }
    }
  } else {
    __syncthreads();
#pragma unroll
    for (int nI = 0; nI < 4; ++nI) {
      const int hl = wn * 64 + nI * 16 + fr;
      const float bcol = bias[hc0 + hl];
#pragma unroll
      for (int mI = 0; mI < 8; ++mI) {
        const int tl = wm * 128 + mI * 16 + fq * 4;
        s16x4 pk = { f2bf(fmaxf(acc[mI][nI][0] + bcol, 0.f)),
                     f2bf(fmaxf(acc[mI][nI][1] + bcol, 0.f)),
                     f2bf(fmaxf(acc[mI][nI][2] + bcol, 0.f)),
                     f2bf(fmaxf(acc[mI][nI][3] + bcol, 0.f)) };
        *(s16x4*)(lds + hl * 264 + tl) = pk;
      }
    }
    __syncthreads();
    const int h = tid >> 1, half = tid & 1;
    const long bb = m0 >> 10;
    short* dst = vT + ((bb * NH) + hc0 + h) * NS + (m0 & 1023) + half * 128;
    const short* src = lds + h * 264 + half * 128;
#pragma unroll
    for (int j = 0; j < 16; ++j)
      *(s16x8*)(dst + j * 8) = *(const s16x8*)(src + j * 8);
  }
}

// ---- e[b,s,t] = f16(q.k - 1e10*(1-mask) - 40)  (BK=32 core, 2 blocks/CU)
__global__ __launch_bounds__(512, 4) void escore_kernel(const short* __restrict__ q,
    const short* __restrict__ k, const int* __restrict__ amask, short* __restrict__ e) {
  __shared__ short lds[32768];
  const int flat = blockIdx.z * 16 + blockIdx.y * 4 + blockIdx.x;
  const int gid  = (flat & 7) * 64 + (flat >> 3);
  const int b = gid >> 4, mt = (gid >> 2) & 3, nt = gid & 3;
  const short* gA = q + (long)b * NS * NH;
  const short* gB = k + (long)b * NS * NH;
  const long m0 = (long)mt * 256;
  const long n0 = (long)nt * 256;
  GEMM32_MAIN();
  short* eb = e + (long)b * NS * NS;
#pragma unroll
  for (int mI = 0; mI < 8; ++mI)
#pragma unroll
    for (int nI = 0; nI < 4; ++nI) {
      const long col = n0 + wn * 64 + nI * 16 + fr;
      const float mb = -1e10f * (1.f - (float)amask[b * NS + col]) - 40.f;
#pragma unroll
      for (int r = 0; r < 4; ++r) {
        const long row = m0 + wm * 128 + mI * 16 + fq * 4 + r;
        eb[row * NS + col] = f2h(fmaxf(acc[mI][nI][r] + mb, -60000.f));
      }
    }
}

// ---- row softmax (f16 in): a = bf16(exp(e - max)), inv_sum = 1/sum
__global__ __launch_bounds__(256) void softmax_kernel(const short* __restrict__ e,
    short* __restrict__ a, float* __restrict__ inv_sum) {
  const long row = blockIdx.x;
  const int tid = threadIdx.x;
  __shared__ float red[4];
  s16x4 ev = *(const s16x4*)(e + row * NS + tid * 4);
  float v0 = h2f(ev[0]), v1 = h2f(ev[1]), v2 = h2f(ev[2]), v3 = h2f(ev[3]);
  float m = block_reduce_max(fmaxf(fmaxf(v0, v1), fmaxf(v2, v3)), red);
  float p0 = expf(v0 - m), p1 = expf(v1 - m);
  float p2 = expf(v2 - m), p3 = expf(v3 - m);
  float s = block_reduce_sum(p0 + p1 + p2 + p3, red);
  s16x4 o = { f2bf(p0), f2bf(p1), f2bf(p2), f2bf(p3) };
  *(s16x4*)(a + row * NS + tid * 4) = o;
  if (tid == 0) inv_sum[row] = 1.f / s;
}

// ---- hidden = (a @ v) * inv_sum + normed + fused pred partials (BK=32 core)
__global__ __launch_bounds__(512, 4) void av_kernel(const short* __restrict__ a,
    const short* __restrict__ vT, const float* __restrict__ inv_sum,
    const short* __restrict__ normed, const float* __restrict__ Wo,
    float* __restrict__ hid, float* __restrict__ pred_part) {
  __shared__ short lds[32768];
  const int flat = blockIdx.z * 16 + blockIdx.y * 4 + blockIdx.x;
  const int gid  = (flat & 7) * 64 + (flat >> 3);
  const int b = gid >> 4, mt = (gid >> 2) & 3, nt = gid & 3;
  const short* gA = a + (long)b * NS * NS;
  const short* gB = vT + (long)b * NH * NS;
  const long m0 = (long)mt * 256;
  const long n0 = (long)nt * 256;
  GEMM32_MAIN();
  float pp[8][4];
#pragma unroll
  for (int mI = 0; mI < 8; ++mI)
#pragma unroll
    for (int r = 0; r < 4; ++r) pp[mI][r] = 0.f;
#pragma unroll
  for (int nI = 0; nI < 4; ++nI) {
    const long col = n0 + wn * 64 + nI * 16 + fr;
    const float wo = Wo[col];
#pragma unroll
    for (int mI = 0; mI < 8; ++mI)
#pragma unroll
      for (int r = 0; r < 4; ++r) {
        const long row = m0 + wm * 128 + mI * 16 + fq * 4 + r;
        const long gi = ((long)b * NS + row) * NH + col;
        float hv = acc[mI][nI][r] * inv_sum[b * NS + row] + bf2f(normed[gi]);
        hid[gi] = hv;
        pp[mI][r] += hv * wo;
      }
  }
#pragma unroll
  for (int mI = 0; mI < 8; ++mI)
#pragma unroll
    for (int r = 0; r < 4; ++r) {
      float v = pp[mI][r];
      v += __shfl_xor(v, 1);
      v += __shfl_xor(v, 2);
      v += __shfl_xor(v, 4);
      v += __shfl_xor(v, 8);
      if (fr == 0)
        pred_part[((long)nt * 4 + wn) * (NB * NS) + (long)b * NS + m0 +
                  wm * 128 + mI * 16 + fq * 4 + r] = v;
    }
}

// ---- pred[row] = sum of 16 partials + bo
__global__ __launch_bounds__(256) void pred_finish_kernel(const float* __restrict__ pp,
    const float* __restrict__ bo, float* __restrict__ pred) {
  const int i = (blockIdx.x * 256 + threadIdx.x) * 4;
  const float bz = bo[0];
  f32x4 o = { bz, bz, bz, bz };
#pragma unroll
  for (int j = 0; j < 16; ++j) {
    f32x4 a = *(const f32x4*)(pp + (long)j * (NB * NS) + i);
    o[0] += a[0]; o[1] += a[1]; o[2] += a[2]; o[3] += a[3];
  }
  *(f32x4*)(pred + i) = o;
}

extern "C" void kernel_launch(void* const* d_in, const int* in_sizes, int n_in,
                              void* d_out, int out_size, void* d_ws, size_t ws_size,
                              hipStream_t stream) {
  (void)in_sizes; (void)n_in; (void)out_size; (void)ws_size;
  const int*   relation = (const int*)d_in[0];
  const float* x        = (const float*)d_in[1];
  const int*   sub_head = (const int*)d_in[2];
  const int*   sub_tail = (const int*)d_in[3];
  const int*   amask    = (const int*)d_in[4];
  const float* rel_emb  = (const float*)d_in[5];
  const float* Wrf      = (const float*)d_in[6];
  const float* brf      = (const float*)d_in[7];
  const float* cln_w    = (const float*)d_in[8];
  const float* cln_b    = (const float*)d_in[9];
  const float* Wwd      = (const float*)d_in[10];
  const float* Wbd      = (const float*)d_in[11];
  const float* Wq       = (const float*)d_in[12];
  const float* bq       = (const float*)d_in[13];
  const float* Wk       = (const float*)d_in[14];
  const float* bk       = (const float*)d_in[15];
  const float* Wv       = (const float*)d_in[16];
  const float* bv       = (const float*)d_in[17];
  const float* Wo       = (const float*)d_in[18];
  const float* bo       = (const float*)d_in[19];

  char* ws = (char*)d_ws;
  short* wqkv_bf = (short*)ws;               // 3M shorts [3072][1024]
  float* cond    = (float*)(ws + 6291456);   // [32, 2048]
  float* wln     = cond + 32 * 2048;         // [32, 1024]
  float* bln     = wln + 32 * 1024;          // [32, 1024]
  float* inv_sum = bln + 32 * 1024;          // [32768]
  short* normed  = (short*)(inv_sum + 32768);        // 33.5M bf16
  short* qb      = normed + 33554432;                // q, later reused as 'a'
  short* kb      = qb + 33554432;
  short* vT      = kb + 33554432;                    // transposed v
  short* e       = vT + 33554432;                    // 33.5M f16 (shifted -40)
  float* pred_part = (float*)(e + 33554432);         // [16][32768] f32

  float* pred = (float*)d_out;
  float* hid  = pred + 32768;

  prep_kernel<<<4128, 256, 0, stream>>>(relation, x, sub_head, sub_tail,
                                        rel_emb, Wrf, brf, cond,
                                        Wq, Wk, Wv, wqkv_bf);
  wb_kernel<<<NH, 256, 0, stream>>>(cond, Wwd, Wbd, cln_w, cln_b, wln, bln);
  ln_kernel<<<NB * NS, 256, 0, stream>>>(x, wln, bln, normed);
  qkv_kernel<<<dim3(12, 128), 512, 0, stream>>>(normed, wqkv_bf,
                                                bq, bk, bv, qb, kb, vT);
  escore_kernel<<<dim3(4, 4, 32), 512, 0, stream>>>(qb, kb, amask, e);
  softmax_kernel<<<NB * NS, 256, 0, stream>>>(e, qb, inv_sum);
  av_kernel<<<dim3(4, 4, 32), 512, 0, stream>>>(qb, vT, inv_sum, normed, Wo,
                                                hid, pred_part);
  pred_finish_kernel<<<32, 256, 0, stream>>>(pred_part, bo, pred);
}

// Round 13
// 498.277 us; speedup vs baseline: 3.9732x; 3.9732x over previous
//
#include <hip/hip_runtime.h>
#include <hip/hip_bf16.h>
#include <hip/hip_fp16.h>

#define NB 32
#define NS 1024
#define NH 1024

typedef short s16x4 __attribute__((ext_vector_type(4)));
typedef short s16x8 __attribute__((ext_vector_type(8)));
typedef float f32x4 __attribute__((ext_vector_type(4)));

typedef __attribute__((address_space(3))) void lds_void;
typedef const __attribute__((address_space(1))) void gmem_void;

__device__ __forceinline__ short f2bf(float f) {
  __hip_bfloat16 h = __float2bfloat16(f);
  return *reinterpret_cast<short*>(&h);
}
__device__ __forceinline__ float bf2f(short s) {
  union { unsigned u; float f; } cv;
  cv.u = ((unsigned)(unsigned short)s) << 16;
  return cv.f;
}
__device__ __forceinline__ short f2h(float f) {
  __half h = __float2half_rn(f);
  return *reinterpret_cast<short*>(&h);
}
__device__ __forceinline__ float h2f(short s) {
  __half h = *reinterpret_cast<__half*>(&s);
  return __half2float(h);
}

__device__ __forceinline__ float wave_reduce_sum(float v) {
#pragma unroll
  for (int o = 32; o; o >>= 1) v += __shfl_xor(v, o);
  return v;
}
__device__ __forceinline__ float wave_reduce_max(float v) {
#pragma unroll
  for (int o = 32; o; o >>= 1) v = fmaxf(v, __shfl_xor(v, o));
  return v;
}
__device__ __forceinline__ float block_reduce_sum(float v, float* red) {
  v = wave_reduce_sum(v);
  __syncthreads();
  if ((threadIdx.x & 63) == 0) red[threadIdx.x >> 6] = v;
  __syncthreads();
  return red[0] + red[1] + red[2] + red[3];
}
__device__ __forceinline__ float block_reduce_max(float v, float* red) {
  v = wave_reduce_max(v);
  __syncthreads();
  if ((threadIdx.x & 63) == 0) red[threadIdx.x >> 6] = v;
  __syncthreads();
  return fmaxf(fmaxf(red[0], red[1]), fmaxf(red[2], red[3]));
}

// ==================== 256x256 8-phase bf16 GEMM core (r8 + peeled tail) ====
// C = A[M,1024] * B[N,1024]^T. 512 threads = 8 waves (2M x 4N).
// Per wave: 128x64 output = acc[8][4] (128 VGPRs — so 1 block/CU by VGPR;
// r12 lesson: 2-blocks/CU is impossible at this tile size, acc alone is 128).
// BK=64, 2 K-tiles/iter, double-buffered LDS (128 KiB), st-swizzled
// (col8 ^= row&7) on both gload-source and ds_read. A-fragments pre-read one
// phase ahead (post-BAR1) to overlap MFMA. Tail (it=7) peeled: 6 wrap-around
// STAGEs dropped, waits become vmcnt(0).

#define BAR1 do { __builtin_amdgcn_s_barrier();                              \
                  asm volatile("s_waitcnt lgkmcnt(0)" ::: "memory");         \
                  __builtin_amdgcn_sched_barrier(0); } while (0)
#define BAR2 do { __builtin_amdgcn_s_barrier();                              \
                  asm volatile("" ::: "memory"); } while (0)
#define VW   asm volatile("s_waitcnt vmcnt(4)" ::: "memory")
#define VW2  asm volatile("s_waitcnt vmcnt(2)" ::: "memory")
#define VW0  asm volatile("s_waitcnt vmcnt(0)" ::: "memory")

#define GEMM_PRE()                                                           \
  const int tid  = threadIdx.x;                                              \
  const int lane = tid & 63;                                                 \
  const int w    = tid >> 6;                                                 \
  const int wm   = w >> 2, wn = w & 3;                                       \
  const int fr   = lane & 15, fq = lane >> 4;                                \
  const long tA  = (long)(tid >> 3) * 1024 +                                 \
                   (((tid & 7) ^ ((tid >> 3) & 7)) << 3);                    \
  const int kc0  = (fq * 8) ^ ((fr & 7) * 8);                                \
  const int kc1  = (fq * 8 + 32) ^ ((fr & 7) * 8);                           \
  const int rdA  = wm * 8192 + fr * 64;                                      \
  const int rdB  = 16384 + (wn >> 1) * 8192 + (wn & 1) * 4096 + fr * 64;     \
  const int wsl  = w * 512;                                                  \
  f32x4 acc[8][4];                                                           \
  s16x8 aF[2][4][2], bF[2][2][2];                                            \
  _Pragma("unroll") for (int i_ = 0; i_ < 8; ++i_)                           \
    _Pragma("unroll") for (int j_ = 0; j_ < 4; ++j_)                         \
      acc[i_][j_] = (f32x4){0.f, 0.f, 0.f, 0.f};

#define STAGE(d, isB, h, kt)                                                 \
  do {                                                                       \
    const short* _g = ((isB) ? gB + (n0 + (h) * 128) * 1024                  \
                             : gA + (m0 + (h) * 128) * 1024) +               \
                      (long)(kt) * 64 + tA;                                  \
    short* _l = lds + (d) * 32768 + (isB) * 16384 + (h) * 8192 + wsl;        \
    __builtin_amdgcn_global_load_lds((gmem_void*)_g, (lds_void*)_l,          \
                                     16, 0, 0);                              \
    __builtin_amdgcn_global_load_lds((gmem_void*)(_g + 65536),               \
                                     (lds_void*)(_l + 4096), 16, 0, 0);      \
  } while (0)

#define RD_A(d, mq)                                                          \
  _Pragma("unroll") for (int mi = 0; mi < 4; ++mi) {                         \
    aF[mq][mi][0] = *(const s16x8*)(lds + (d) * 32768 + rdA + (mq) * 4096 +  \
                                    mi * 1024 + kc0);                        \
    aF[mq][mi][1] = *(const s16x8*)(lds + (d) * 32768 + rdA + (mq) * 4096 +  \
                                    mi * 1024 + kc1);                        \
  }
#define RD_B(d, nq)                                                          \
  _Pragma("unroll") for (int ni = 0; ni < 2; ++ni) {                         \
    bF[nq][ni][0] = *(const s16x8*)(lds + (d) * 32768 + rdB + (nq) * 2048 +  \
                                    ni * 1024 + kc0);                        \
    bF[nq][ni][1] = *(const s16x8*)(lds + (d) * 32768 + rdB + (nq) * 2048 +  \
                                    ni * 1024 + kc1);                        \
  }
#define MMA(mq, nq)                                                          \
  do {                                                                       \
    __builtin_amdgcn_s_setprio(1);                                           \
    _Pragma("unroll") for (int kk = 0; kk < 2; ++kk)                         \
      _Pragma("unroll") for (int mi = 0; mi < 4; ++mi)                       \
        _Pragma("unroll") for (int ni = 0; ni < 2; ++ni)                     \
          acc[(mq) * 4 + mi][(nq) * 2 + ni] =                                \
              __builtin_amdgcn_mfma_f32_16x16x32_bf16(                       \
                  aF[mq][mi][kk], bF[nq][ni][kk],                            \
                  acc[(mq) * 4 + mi][(nq) * 2 + ni], 0, 0, 0);               \
    __builtin_amdgcn_s_setprio(0);                                           \
  } while (0)

#define GEMM_MAIN()                                                          \
  GEMM_PRE();                                                                \
  STAGE(0, 1, 0, 0); STAGE(0, 1, 1, 0); STAGE(0, 0, 0, 0); STAGE(0, 0, 1, 0);\
  STAGE(1, 1, 0, 1); STAGE(1, 1, 1, 1);                                      \
  VW; BAR2;                                                                  \
  RD_A(0, 0);                                                                \
  for (int it = 0; it < 7; ++it) {                                           \
    const int t1 = 2 * it + 1, t2 = 2 * it + 2, t3 = 2 * it + 3;             \
    RD_B(0, 0); STAGE(1, 0, 0, t1); BAR1; MMA(0, 0); BAR2;                   \
    RD_B(0, 1); STAGE(1, 0, 1, t1); BAR1; MMA(0, 1); BAR2;                   \
    RD_A(0, 1); STAGE(0, 1, 0, t2); BAR1; MMA(1, 1); BAR2;                   \
    VW2;        STAGE(0, 1, 1, t2); BAR1; RD_A(1, 0); MMA(1, 0); BAR2;       \
    RD_B(1, 0); STAGE(0, 0, 0, t2); BAR1; MMA(0, 0); BAR2;                   \
    RD_B(1, 1); STAGE(0, 0, 1, t2); BAR1; MMA(0, 1); BAR2;                   \
    RD_A(1, 1); STAGE(1, 1, 0, t3); BAR1; MMA(1, 1); BAR2;                   \
    VW2;        STAGE(1, 1, 1, t3); BAR1; RD_A(0, 0); MMA(1, 0); BAR2;       \
  }                                                                          \
  RD_B(0, 0); STAGE(1, 0, 0, 15); BAR1; MMA(0, 0); BAR2;                     \
  RD_B(0, 1); STAGE(1, 0, 1, 15); BAR1; MMA(0, 1); BAR2;                     \
  RD_A(0, 1);                     BAR1; MMA(1, 1); BAR2;                     \
  VW0;                            BAR1; RD_A(1, 0); MMA(1, 0); BAR2;         \
  RD_B(1, 0);                     BAR1; MMA(0, 0); BAR2;                     \
  RD_B(1, 1);                     BAR1; MMA(0, 1); BAR2;                     \
  RD_A(1, 1);                     BAR1; MMA(1, 1); BAR2;                     \
  VW0;                            BAR1; MMA(1, 0); BAR2;

// epilogue index map: row = m0 + wm*128 + mI*16 + fq*4 + r
//                     col = n0 + wn*64  + nI*16 + fr

// ---- prep: [0,1024) rel-GEMV one block per g (Wrf row staged once, all 32 b);
//            [1024,1056) sub-gather per b; [1056,4128) weights f32->bf16.
__global__ __launch_bounds__(256) void prep_kernel(const int* __restrict__ relation,
    const float* __restrict__ x, const int* __restrict__ sub_head,
    const int* __restrict__ sub_tail, const float* __restrict__ rel_emb,
    const float* __restrict__ Wrf, const float* __restrict__ brf,
    float* __restrict__ cond,
    const float* __restrict__ Wq, const float* __restrict__ Wk,
    const float* __restrict__ Wv, short* __restrict__ wout) {
  const int blk = blockIdx.x;
  const int tid = threadIdx.x;
  if (blk >= 1056) {
    long i = ((long)(blk - 1056) * 256 + tid) * 4;
    int seg = (int)(i >> 20);
    long off = i & 1048575;
    const float* src = seg == 0 ? Wq : (seg == 1 ? Wk : Wv);
    f32x4 v = *(const f32x4*)(src + off);
    s16x4 o = { f2bf(v[0]), f2bf(v[1]), f2bf(v[2]), f2bf(v[3]) };
    *(s16x4*)(wout + i) = o;
    return;
  }
  if (blk >= 1024) {
    const int b = blk - 1024;
    const int sh = sub_head[b], st = sub_tail[b];
    for (int h = tid * 4; h < NH; h += 1024) {
      f32x4 a = *(const f32x4*)(x + ((long)b * NS + sh) * NH + h);
      f32x4 c = *(const f32x4*)(x + ((long)b * NS + st) * NH + h);
      f32x4 o = { 0.5f * (a[0] + c[0]), 0.5f * (a[1] + c[1]),
                  0.5f * (a[2] + c[2]), 0.5f * (a[3] + c[3]) };
      *(f32x4*)(cond + b * 2 * NH + NH + h) = o;
    }
    return;
  }
  const int g = blk;
  __shared__ float wr[NH];
  for (int h = tid * 4; h < NH; h += 1024)
    *(f32x4*)(wr + h) = *(const f32x4*)(Wrf + (long)g * NH + h);
  __syncthreads();
  const int lane = tid & 63, wid = tid >> 6;
  const float bg = brf[g];
  for (int b = wid; b < NB; b += 4) {
    const int rid = relation[b];
    const float* re = rel_emb + (long)rid * NH;
    float s = 0.f;
#pragma unroll
    for (int h = lane * 4; h < NH; h += 256) {
      f32x4 rv = *(const f32x4*)(re + h);
      f32x4 wv = *(const f32x4*)(wr + h);
      s += rv[0] * wv[0] + rv[1] * wv[1] + rv[2] * wv[2] + rv[3] * wv[3];
    }
    s = wave_reduce_sum(s);
    if (lane == 0) cond[b * 2 * NH + g] = fminf(fmaxf(s + bg, 0.f), 6.f);
  }
}

// ---- wln/bln[b,g] = cond[b,:] . W{wd,bd}[g,:] + cln_{w,b}[g]
__global__ __launch_bounds__(256) void wb_kernel(const float* __restrict__ cond,
    const float* __restrict__ Wwd, const float* __restrict__ Wbd,
    const float* __restrict__ cln_w, const float* __restrict__ cln_b,
    float* __restrict__ wln, float* __restrict__ bln) {
  const int g = blockIdx.x;
  const int tid = threadIdx.x;
  __shared__ float wrow[2 * NH];
  __shared__ float brow[2 * NH];
  for (int i = tid * 4; i < 2 * NH; i += 1024) {
    *(f32x4*)(wrow + i) = *(const f32x4*)(Wwd + (long)g * 2 * NH + i);
    *(f32x4*)(brow + i) = *(const f32x4*)(Wbd + (long)g * 2 * NH + i);
  }
  __syncthreads();
  const int lane = tid & 63, wid = tid >> 6;
  const float cw = cln_w[g], cb = cln_b[g];
  for (int b = wid; b < NB; b += 4) {
    float sw = 0.f, sb = 0.f;
#pragma unroll
    for (int c = lane * 4; c < 2 * NH; c += 256) {
      f32x4 cv = *(const f32x4*)(cond + b * 2 * NH + c);
      f32x4 wv = *(const f32x4*)(wrow + c);
      f32x4 bv = *(const f32x4*)(brow + c);
      sw += cv[0] * wv[0] + cv[1] * wv[1] + cv[2] * wv[2] + cv[3] * wv[3];
      sb += cv[0] * bv[0] + cv[1] * bv[1] + cv[2] * bv[2] + cv[3] * bv[3];
    }
    sw = wave_reduce_sum(sw);
    sb = wave_reduce_sum(sb);
    if (lane == 0) {
      wln[b * NH + g] = sw + cw;
      bln[b * NH + g] = sb + cb;
    }
  }
}

// ---- conditional LayerNorm -> normed (bf16)
__global__ __launch_bounds__(256) void ln_kernel(const float* __restrict__ x,
    const float* __restrict__ wln, const float* __restrict__ bln, short* __restrict__ normed) {
  const long row = blockIdx.x;
  const int tid = threadIdx.x;
  const long b = row >> 10;
  __shared__ float red[4];
  f32x4 v = *(const f32x4*)(x + row * NH + tid * 4);
  float mean = block_reduce_sum(v[0] + v[1] + v[2] + v[3], red) * (1.f / NH);
  float c0 = v[0] - mean, c1 = v[1] - mean, c2 = v[2] - mean, c3 = v[3] - mean;
  float var = block_reduce_sum(c0 * c0 + c1 * c1 + c2 * c2 + c3 * c3, red) * (1.f / NH);
  float rstd = rsqrtf(var + 1e-12f);
  f32x4 wv = *(const f32x4*)(wln + b * NH + tid * 4);
  f32x4 bv = *(const f32x4*)(bln + b * NH + tid * 4);
  s16x4 o = { f2bf(c0 * rstd * wv[0] + bv[0]), f2bf(c1 * rstd * wv[1] + bv[1]),
              f2bf(c2 * rstd * wv[2] + bv[2]), f2bf(c3 * rstd * wv[3] + bv[3]) };
  *(s16x4*)(normed + row * NH + tid * 4) = o;
}

// ---- fused qkv GEMM: 1536 wgs, XCD-chunked bijective swizzle.
// v is transposed via LDS ([256 h][264-pad t]) for coalesced vT stores.
__global__ __launch_bounds__(512, 2) void qkv_kernel(const short* __restrict__ A,
    const short* __restrict__ Wqkv,
    const float* __restrict__ bq, const float* __restrict__ bk, const float* __restrict__ bv,
    short* __restrict__ q, short* __restrict__ k, short* __restrict__ vT) {
  __shared__ short lds[67584];  // 135168 B: 128K staging, reused for vT transpose
  const int flat = blockIdx.y * 12 + blockIdx.x;
  const int gid  = (flat & 7) * 192 + (flat >> 3);
  const int mt = gid / 12, nt = gid % 12;
  const short* gA = A;
  const short* gB = Wqkv;
  const long n0 = (long)nt * 256;
  const long m0 = (long)mt * 256;
  GEMM_MAIN();
  const int z = nt >> 2;
  const long hc0 = (long)(nt & 3) * 256;
  const float* bias = z == 0 ? bq : (z == 1 ? bk : bv);
  if (z < 2) {
    short* dst = z == 0 ? q : k;
#pragma unroll
    for (int nI = 0; nI < 4; ++nI) {
      const long col = hc0 + wn * 64 + nI * 16 + fr;
      const float bcol = bias[col];
#pragma unroll
      for (int mI = 0; mI < 8; ++mI)
#pragma unroll
        for (int r = 0; r < 4; ++r) {
          const long row = m0 + wm * 128 + mI * 16 + fq * 4 + r;
          dst[row * NH + col] = f2bf(fmaxf(acc[mI][nI][r] + bcol, 0.f));
        }
    }
  } else {
    // all stages drained (peeled tail ends vmcnt(0)); sync then reuse LDS
    __syncthreads();
#pragma unroll
    for (int nI = 0; nI < 4; ++nI) {
      const int hl = wn * 64 + nI * 16 + fr;
      const float bcol = bias[hc0 + hl];
#pragma unroll
      for (int mI = 0; mI < 8; ++mI) {
        const int tl = wm * 128 + mI * 16 + fq * 4;
        s16x4 pk = { f2bf(fmaxf(acc[mI][nI][0] + bcol, 0.f)),
                     f2bf(fmaxf(acc[mI][nI][1] + bcol, 0.f)),
                     f2bf(fmaxf(acc[mI][nI][2] + bcol, 0.f)),
                     f2bf(fmaxf(acc[mI][nI][3] + bcol, 0.f)) };
        *(s16x4*)(lds + hl * 264 + tl) = pk;
      }
    }
    __syncthreads();
    const int h = tid >> 1, half = tid & 1;
    const long bb = m0 >> 10;
    short* dst = vT + ((bb * NH) + hc0 + h) * NS + (m0 & 1023) + half * 128;
    const short* src = lds + h * 264 + half * 128;
#pragma unroll
    for (int j = 0; j < 16; ++j)
      *(s16x8*)(dst + j * 8) = *(const s16x8*)(src + j * 8);
  }
}

// ---- e[b,s,t] = f16(q.k - 1e10*(1-mask) - 40), clamped to -60000
__global__ __launch_bounds__(512, 2) void escore_kernel(const short* __restrict__ q,
    const short* __restrict__ k, const int* __restrict__ amask, short* __restrict__ e) {
  __shared__ short lds[65536];
  const int flat = blockIdx.z * 16 + blockIdx.y * 4 + blockIdx.x;
  const int gid  = (flat & 7) * 64 + (flat >> 3);
  const int b = gid >> 4, mt = (gid >> 2) & 3, nt = gid & 3;
  const short* gA = q + (long)b * NS * NH;
  const short* gB = k + (long)b * NS * NH;
  const long m0 = (long)mt * 256;
  const long n0 = (long)nt * 256;
  GEMM_MAIN();
  short* eb = e + (long)b * NS * NS;
#pragma unroll
  for (int mI = 0; mI < 8; ++mI)
#pragma unroll
    for (int nI = 0; nI < 4; ++nI) {
      const long col = n0 + wn * 64 + nI * 16 + fr;
      const float mb = -1e10f * (1.f - (float)amask[b * NS + col]) - 40.f;
#pragma unroll
      for (int r = 0; r < 4; ++r) {
        const long row = m0 + wm * 128 + mI * 16 + fq * 4 + r;
        eb[row * NS + col] = f2h(fmaxf(acc[mI][nI][r] + mb, -60000.f));
      }
    }
}

// ---- row softmax (f16 in): a = bf16(exp(e - max)), inv_sum = 1/sum
__global__ __launch_bounds__(256) void softmax_kernel(const short* __restrict__ e,
    short* __restrict__ a, float* __restrict__ inv_sum) {
  const long row = blockIdx.x;
  const int tid = threadIdx.x;
  __shared__ float red[4];
  s16x4 ev = *(const s16x4*)(e + row * NS + tid * 4);
  float v0 = h2f(ev[0]), v1 = h2f(ev[1]), v2 = h2f(ev[2]), v3 = h2f(ev[3]);
  float m = block_reduce_max(fmaxf(fmaxf(v0, v1), fmaxf(v2, v3)), red);
  float p0 = expf(v0 - m), p1 = expf(v1 - m);
  float p2 = expf(v2 - m), p3 = expf(v3 - m);
  float s = block_reduce_sum(p0 + p1 + p2 + p3, red);
  s16x4 o = { f2bf(p0), f2bf(p1), f2bf(p2), f2bf(p3) };
  *(s16x4*)(a + row * NS + tid * 4) = o;
  if (tid == 0) inv_sum[row] = 1.f / s;
}

// ---- hidden = (a @ v) * inv_sum + normed (f32, into d_out)
//      + fused pred partials, one slice per (n-tile, wave-column).
__global__ __launch_bounds__(512, 2) void av_kernel(const short* __restrict__ a,
    const short* __restrict__ vT, const float* __restrict__ inv_sum,
    const short* __restrict__ normed, const float* __restrict__ Wo,
    float* __restrict__ hid, float* __restrict__ pred_part) {
  __shared__ short lds[65536];
  const int flat = blockIdx.z * 16 + blockIdx.y * 4 + blockIdx.x;
  const int gid  = (flat & 7) * 64 + (flat >> 3);
  const int b = gid >> 4, mt = (gid >> 2) & 3, nt = gid & 3;
  const short* gA = a + (long)b * NS * NS;
  const short* gB = vT + (long)b * NH * NS;
  const long m0 = (long)mt * 256;
  const long n0 = (long)nt * 256;
  GEMM_MAIN();
  float pp[8][4];
#pragma unroll
  for (int mI = 0; mI < 8; ++mI)
#pragma unroll
    for (int r = 0; r < 4; ++r) pp[mI][r] = 0.f;
#pragma unroll
  for (int nI = 0; nI < 4; ++nI) {
    const long col = n0 + wn * 64 + nI * 16 + fr;
    const float wo = Wo[col];
#pragma unroll
    for (int mI = 0; mI < 8; ++mI)
#pragma unroll
      for (int r = 0; r < 4; ++r) {
        const long row = m0 + wm * 128 + mI * 16 + fq * 4 + r;
        const long gi = ((long)b * NS + row) * NH + col;
        float hv = acc[mI][nI][r] * inv_sum[b * NS + row] + bf2f(normed[gi]);
        hid[gi] = hv;
        pp[mI][r] += hv * wo;
      }
  }
#pragma unroll
  for (int mI = 0; mI < 8; ++mI)
#pragma unroll
    for (int r = 0; r < 4; ++r) {
      float v = pp[mI][r];
      v += __shfl_xor(v, 1);
      v += __shfl_xor(v, 2);
      v += __shfl_xor(v, 4);
      v += __shfl_xor(v, 8);
      if (fr == 0)
        pred_part[((long)nt * 4 + wn) * (NB * NS) + (long)b * NS + m0 +
                  wm * 128 + mI * 16 + fq * 4 + r] = v;
    }
}

// ---- pred[row] = sum of 16 partials + bo
__global__ __launch_bounds__(256) void pred_finish_kernel(const float* __restrict__ pp,
    const float* __restrict__ bo, float* __restrict__ pred) {
  const int i = (blockIdx.x * 256 + threadIdx.x) * 4;
  const float bz = bo[0];
  f32x4 o = { bz, bz, bz, bz };
#pragma unroll
  for (int j = 0; j < 16; ++j) {
    f32x4 a = *(const f32x4*)(pp + (long)j * (NB * NS) + i);
    o[0] += a[0]; o[1] += a[1]; o[2] += a[2]; o[3] += a[3];
  }
  *(f32x4*)(pred + i) = o;
}

extern "C" void kernel_launch(void* const* d_in, const int* in_sizes, int n_in,
                              void* d_out, int out_size, void* d_ws, size_t ws_size,
                              hipStream_t stream) {
  (void)in_sizes; (void)n_in; (void)out_size; (void)ws_size;
  const int*   relation = (const int*)d_in[0];
  const float* x        = (const float*)d_in[1];
  const int*   sub_head = (const int*)d_in[2];
  const int*   sub_tail = (const int*)d_in[3];
  const int*   amask    = (const int*)d_in[4];
  const float* rel_emb  = (const float*)d_in[5];
  const float* Wrf      = (const float*)d_in[6];
  const float* brf      = (const float*)d_in[7];
  const float* cln_w    = (const float*)d_in[8];
  const float* cln_b    = (const float*)d_in[9];
  const float* Wwd      = (const float*)d_in[10];
  const float* Wbd      = (const float*)d_in[11];
  const float* Wq       = (const float*)d_in[12];
  const float* bq       = (const float*)d_in[13];
  const float* Wk       = (const float*)d_in[14];
  const float* bk       = (const float*)d_in[15];
  const float* Wv       = (const float*)d_in[16];
  const float* bv       = (const float*)d_in[17];
  const float* Wo       = (const float*)d_in[18];
  const float* bo       = (const float*)d_in[19];

  char* ws = (char*)d_ws;
  short* wqkv_bf = (short*)ws;               // 3M shorts [3072][1024]
  float* cond    = (float*)(ws + 6291456);   // [32, 2048]
  float* wln     = cond + 32 * 2048;         // [32, 1024]
  float* bln     = wln + 32 * 1024;          // [32, 1024]
  float* inv_sum = bln + 32 * 1024;          // [32768]
  short* normed  = (short*)(inv_sum + 32768);        // 33.5M bf16
  short* qb      = normed + 33554432;                // q, later reused as 'a'
  short* kb      = qb + 33554432;
  short* vT      = kb + 33554432;                    // transposed v
  short* e       = vT + 33554432;                    // 33.5M f16 (shifted -40)
  float* pred_part = (float*)(e + 33554432);         // [16][32768] f32

  float* pred = (float*)d_out;
  float* hid  = pred + 32768;

  prep_kernel<<<4128, 256, 0, stream>>>(relation, x, sub_head, sub_tail,
                                        rel_emb, Wrf, brf, cond,
                                        Wq, Wk, Wv, wqkv_bf);
  wb_kernel<<<NH, 256, 0, stream>>>(cond, Wwd, Wbd, cln_w, cln_b, wln, bln);
  ln_kernel<<<NB * NS, 256, 0, stream>>>(x, wln, bln, normed);
  qkv_kernel<<<dim3(12, 128), 512, 0, stream>>>(normed, wqkv_bf,
                                                bq, bk, bv, qb, kb, vT);
  escore_kernel<<<dim3(4, 4, 32), 512, 0, stream>>>(qb, kb, amask, e);
  softmax_kernel<<<NB * NS, 256, 0, stream>>>(e, qb, inv_sum);
  av_kernel<<<dim3(4, 4, 32), 512, 0, stream>>>(qb, vT, inv_sum, normed, Wo,
                                                hid, pred_part);
  pred_finish_kernel<<<32, 256, 0, stream>>>(pred_part, bo, pred);
}